// Round 9
// baseline (599.906 us; speedup 1.0000x reference)
//
#include <hip/hip_runtime.h>

#define IN_CH   128
#define HEADS   4
#define OUT_CH  16
#define HID     64
#define NEG_SLOPE 0.2f

#define LDA 136            // padded LDS row stride in bf16 elems

// counting-sort config: destination ranges of 256 nodes
#define RB      8                  // log2(range size)
#define RSZ     256                // nodes per destination range
#define NRANGE  256                // padded range count (196 real for N=50000)
#define SEG     4096               // edges per sort block
// ebuf packing: (dlocal << 23) | src   — src < 2^23, dlocal < 2^8

typedef __attribute__((ext_vector_type(8))) short short8;     // 8 bf16
typedef __attribute__((ext_vector_type(4))) float float4v;    // 4 fp32 acc

__device__ __forceinline__ unsigned short f2bf(float f) {
    unsigned int u = __float_as_uint(f);
    u += 0x7FFFu + ((u >> 16) & 1u);
    return (unsigned short)(u >> 16);
}
__device__ __forceinline__ float bf2f(unsigned short u) {
    return __uint_as_float(((unsigned int)u) << 16);
}

// ---------------------------------------------------------------------------
// Kernel 1: proj = x @ W^T via bf16 MFMA, proj stored bf16; fused asrc/adst.
// Block 0 also zeroes coltot (stream order guarantees it precedes count).
// ---------------------------------------------------------------------------
__global__ __launch_bounds__(256) void proj_mfma_kernel(
    const float* __restrict__ x,
    const float* __restrict__ W,
    const float* __restrict__ att_src,
    const float* __restrict__ att_dst,
    unsigned short* __restrict__ proj,   // [N, 64] bf16
    float* __restrict__ asrc,
    float* __restrict__ adst,
    int* __restrict__ coltot,
    int n_nodes)
{
    __shared__ unsigned short As[64 * LDA];
    __shared__ unsigned short Bs[64 * LDA];

    const int tid = threadIdx.x;
    const int n0  = blockIdx.x * 64;

    if (blockIdx.x == 0 && tid < NRANGE) coltot[tid] = 0;

    #pragma unroll
    for (int i = 0; i < 8; ++i) {
        int idx4 = i * 256 + tid;
        int row  = idx4 >> 5;
        int c4   = (idx4 & 31) * 4;
        float4 v = *(const float4*)(W + row * IN_CH + c4);
        ushort4 o;
        o.x = f2bf(v.x); o.y = f2bf(v.y); o.z = f2bf(v.z); o.w = f2bf(v.w);
        *(ushort4*)(&Bs[row * LDA + c4]) = o;
    }
    #pragma unroll
    for (int i = 0; i < 8; ++i) {
        int idx4 = i * 256 + tid;
        int row  = idx4 >> 5;
        int c4   = (idx4 & 31) * 4;
        int n    = n0 + row;
        float4 v = make_float4(0.f, 0.f, 0.f, 0.f);
        if (n < n_nodes) v = *(const float4*)(x + (size_t)n * IN_CH + c4);
        ushort4 o;
        o.x = f2bf(v.x); o.y = f2bf(v.y); o.z = f2bf(v.z); o.w = f2bf(v.w);
        *(ushort4*)(&As[row * LDA + c4]) = o;
    }
    __syncthreads();

    const int w    = tid >> 6;
    const int lane = tid & 63;
    const int l16  = lane & 15;
    const int quad = lane >> 4;

    float4v acc0 = {0.f,0.f,0.f,0.f};
    float4v acc1 = {0.f,0.f,0.f,0.f};
    float4v acc2 = {0.f,0.f,0.f,0.f};
    float4v acc3 = {0.f,0.f,0.f,0.f};

    const unsigned short* arow = &As[(w * 16 + l16) * LDA + quad * 8];
    const unsigned short* b0   = &Bs[( 0 + l16) * LDA + quad * 8];
    const unsigned short* b1   = &Bs[(16 + l16) * LDA + quad * 8];
    const unsigned short* b2   = &Bs[(32 + l16) * LDA + quad * 8];
    const unsigned short* b3   = &Bs[(48 + l16) * LDA + quad * 8];

    #pragma unroll
    for (int k0 = 0; k0 < IN_CH; k0 += 32) {
        short8 a  = *(const short8*)(arow + k0);
        acc0 = __builtin_amdgcn_mfma_f32_16x16x32_bf16(a, *(const short8*)(b0 + k0), acc0, 0, 0, 0);
        acc1 = __builtin_amdgcn_mfma_f32_16x16x32_bf16(a, *(const short8*)(b1 + k0), acc1, 0, 0, 0);
        acc2 = __builtin_amdgcn_mfma_f32_16x16x32_bf16(a, *(const short8*)(b2 + k0), acc2, 0, 0, 0);
        acc3 = __builtin_amdgcn_mfma_f32_16x16x32_bf16(a, *(const short8*)(b3 + k0), acc3, 0, 0, 0);
    }

    const float as0 = att_src[ 0 + l16], ad0 = att_dst[ 0 + l16];
    const float as1 = att_src[16 + l16], ad1 = att_dst[16 + l16];
    const float as2 = att_src[32 + l16], ad2 = att_dst[32 + l16];
    const float as3 = att_src[48 + l16], ad3 = att_dst[48 + l16];

    #pragma unroll
    for (int r = 0; r < 4; ++r) {
        const int n = n0 + w * 16 + quad * 4 + r;
        const bool ok = (n < n_nodes);
        float v0 = acc0[r], v1 = acc1[r], v2 = acc2[r], v3 = acc3[r];
        if (ok) {
            proj[(size_t)n * HID +  0 + l16] = f2bf(v0);
            proj[(size_t)n * HID + 16 + l16] = f2bf(v1);
            proj[(size_t)n * HID + 32 + l16] = f2bf(v2);
            proj[(size_t)n * HID + 48 + l16] = f2bf(v3);
        }
        float s0 = v0 * as0, s1 = v1 * as1, s2 = v2 * as2, s3 = v3 * as3;
        float d0 = v0 * ad0, d1 = v1 * ad1, d2 = v2 * ad2, d3 = v3 * ad3;
        #pragma unroll
        for (int off = 8; off >= 1; off >>= 1) {
            s0 += __shfl_down(s0, off, 16);
            s1 += __shfl_down(s1, off, 16);
            s2 += __shfl_down(s2, off, 16);
            s3 += __shfl_down(s3, off, 16);
            d0 += __shfl_down(d0, off, 16);
            d1 += __shfl_down(d1, off, 16);
            d2 += __shfl_down(d2, off, 16);
            d3 += __shfl_down(d3, off, 16);
        }
        if (ok && l16 == 0) {
            asrc[n * HEADS + 0] = s0;
            asrc[n * HEADS + 1] = s1;
            asrc[n * HEADS + 2] = s2;
            asrc[n * HEADS + 3] = s3;
            adst[n * HEADS + 0] = d0;
            adst[n * HEADS + 1] = d1;
            adst[n * HEADS + 2] = d2;
            adst[n * HEADS + 3] = d3;
        }
    }
}

// ---------------------------------------------------------------------------
// Sort A: per-block dest-range histogram -> cnt[b][NRANGE]; also accumulates
// global column totals (coltot) so colbase needs no deep loop.
// ---------------------------------------------------------------------------
__global__ __launch_bounds__(256) void count_kernel(
    const int* __restrict__ dst, int* __restrict__ cnt,
    int* __restrict__ coltot, int n_edges)
{
    __shared__ int lc[NRANGE];
    const int b = blockIdx.x;
    lc[threadIdx.x] = 0;
    __syncthreads();
    const int e0 = b * SEG;
    const int e1 = min(e0 + SEG, n_edges);
    for (int e = e0 + threadIdx.x; e < e1; e += 256)
        atomicAdd(&lc[dst[e] >> RB], 1);
    __syncthreads();
    const int v = lc[threadIdx.x];
    cnt[b * NRANGE + threadIdx.x] = v;
    if (v) atomicAdd(&coltot[threadIdx.x], v);
}

// ---------------------------------------------------------------------------
// Sort B1: exclusive scan of coltot -> colbase[257]. One block, 256 thr.
// ---------------------------------------------------------------------------
__global__ __launch_bounds__(256) void colbase_kernel(
    const int* __restrict__ coltot, int* __restrict__ colbase)
{
    __shared__ int wtot[4];
    const int r = threadIdx.x;
    const int v = coltot[r];
    const int lane = r & 63;
    const int wv   = r >> 6;
    int s = v;
    #pragma unroll
    for (int off = 1; off < 64; off <<= 1) {
        int u = __shfl_up(s, off);
        if (lane >= off) s += u;
    }
    if (lane == 63) wtot[wv] = s;
    __syncthreads();
    int add = 0;
    for (int w = 0; w < wv; ++w) add += wtot[w];
    colbase[r] = add + s - v;            // exclusive
    if (r == 255) colbase[256] = add + s;
}

// ---------------------------------------------------------------------------
// Sort B2: per-range column scan over blocks -> off[b][r]. One wave/range.
// ---------------------------------------------------------------------------
__global__ __launch_bounds__(64) void colscan_kernel(
    const int* __restrict__ cnt, const int* __restrict__ colbase,
    int* __restrict__ off, int nblk)
{
    const int r = blockIdx.x;
    const int l = threadIdx.x;
    int carry = colbase[r];
    for (int c0 = 0; c0 < nblk; c0 += 64) {
        const int b = c0 + l;
        int v = (b < nblk) ? cnt[b * NRANGE + r] : 0;
        int s = v;
        #pragma unroll
        for (int o = 1; o < 64; o <<= 1) {
            int u = __shfl_up(s, o);
            if (l >= o) s += u;
        }
        if (b < nblk) off[b * NRANGE + r] = carry + s - v;
        carry += __shfl(s, 63);
    }
}

// ---------------------------------------------------------------------------
// Sort C: bin edges into range-major ebuf, packed (dlocal<<23)|src (uint).
// ---------------------------------------------------------------------------
__global__ __launch_bounds__(256) void bin_kernel(
    const int* __restrict__ src, const int* __restrict__ dst,
    const int* __restrict__ off, unsigned int* __restrict__ ebuf, int n_edges)
{
    __shared__ int lpos[NRANGE];
    const int b = blockIdx.x;
    lpos[threadIdx.x] = off[b * NRANGE + threadIdx.x];
    __syncthreads();
    const int e0 = b * SEG;
    const int e1 = min(e0 + SEG, n_edges);
    for (int e = e0 + threadIdx.x; e < e1; e += 256) {
        const int d = dst[e];
        const unsigned int p = ((unsigned int)(d & (RSZ - 1)) << 23) | (unsigned int)src[e];
        const int slot = atomicAdd(&lpos[d >> RB], 1);
        ebuf[slot] = p;
    }
}

// ---------------------------------------------------------------------------
// Fused aggregation: one block per dest range. LDS fp32 accumulators
// (acc[256][64], bank = channel lane -> conflict-free ds_add_f32).
// Per edge (one per wave per iter, x4 unrolled): 128B coalesced proj gather,
// e = exp(lrelu(asrc[src]+adst[dst])), acc += e*proj, ssum += e.
// Epilogue adds the self-loop analytically, normalizes, writes out densely.
// No csr / deg / row_start / global atomics at all.
// ---------------------------------------------------------------------------
__global__ __launch_bounds__(512) void range_agg_kernel(
    const unsigned int* __restrict__ ebuf,
    const int* __restrict__ colbase,
    const unsigned short* __restrict__ proj,   // bf16
    const float* __restrict__ asrc,
    const float* __restrict__ adst,
    const float* __restrict__ bias,
    float* __restrict__ out,
    int n_nodes)
{
    __shared__ float acc[RSZ * HID];       // 64 KB
    __shared__ float ssum[RSZ * HEADS];    // 4 KB
    __shared__ float ladst[RSZ * HEADS];   // 4 KB

    const int r    = blockIdx.x;
    const int base = r << RB;
    const int lim  = min(RSZ, n_nodes - base);
    const int tid  = threadIdx.x;

    for (int i = tid; i < RSZ * HID; i += 512) acc[i] = 0.f;
    for (int i = tid; i < RSZ * HEADS; i += 512) {
        ssum[i] = 0.f;
        ladst[i] = (i < lim * HEADS) ? adst[base * HEADS + i] : 0.f;
    }
    __syncthreads();

    const int t  = tid & 63;       // channel
    const int h  = t >> 4;         // head
    const int wv = tid >> 6;       // wave 0..7
    const bool slane = (t & 15) == 0;

    const int s0 = colbase[r], s1 = colbase[r + 1];

    int j = s0 + wv;
    for (; j + 24 < s1; j += 32) {
        const unsigned int p0 = ebuf[j];
        const unsigned int p1 = ebuf[j + 8];
        const unsigned int p2 = ebuf[j + 16];
        const unsigned int p3 = ebuf[j + 24];
        const int sc0 = p0 & 0x7FFFFF, dl0 = p0 >> 23;
        const int sc1 = p1 & 0x7FFFFF, dl1 = p1 >> 23;
        const int sc2 = p2 & 0x7FFFFF, dl2 = p2 >> 23;
        const int sc3 = p3 & 0x7FFFFF, dl3 = p3 >> 23;
        const float pr0 = bf2f(proj[(size_t)sc0 * HID + t]);
        const float pr1 = bf2f(proj[(size_t)sc1 * HID + t]);
        const float pr2 = bf2f(proj[(size_t)sc2 * HID + t]);
        const float pr3 = bf2f(proj[(size_t)sc3 * HID + t]);
        float a0 = asrc[sc0 * HEADS + h] + ladst[dl0 * HEADS + h];
        float a1 = asrc[sc1 * HEADS + h] + ladst[dl1 * HEADS + h];
        float a2 = asrc[sc2 * HEADS + h] + ladst[dl2 * HEADS + h];
        float a3 = asrc[sc3 * HEADS + h] + ladst[dl3 * HEADS + h];
        a0 = (a0 > 0.f) ? a0 : NEG_SLOPE * a0;
        a1 = (a1 > 0.f) ? a1 : NEG_SLOPE * a1;
        a2 = (a2 > 0.f) ? a2 : NEG_SLOPE * a2;
        a3 = (a3 > 0.f) ? a3 : NEG_SLOPE * a3;
        const float e0 = __expf(a0);
        const float e1 = __expf(a1);
        const float e2 = __expf(a2);
        const float e3 = __expf(a3);
        atomicAdd(&acc[dl0 * HID + t], e0 * pr0);
        atomicAdd(&acc[dl1 * HID + t], e1 * pr1);
        atomicAdd(&acc[dl2 * HID + t], e2 * pr2);
        atomicAdd(&acc[dl3 * HID + t], e3 * pr3);
        if (slane) {
            atomicAdd(&ssum[dl0 * HEADS + h], e0);
            atomicAdd(&ssum[dl1 * HEADS + h], e1);
            atomicAdd(&ssum[dl2 * HEADS + h], e2);
            atomicAdd(&ssum[dl3 * HEADS + h], e3);
        }
    }
    for (; j < s1; j += 8) {
        const unsigned int p = ebuf[j];
        const int sc = p & 0x7FFFFF, dl = p >> 23;
        const float pr = bf2f(proj[(size_t)sc * HID + t]);
        float a = asrc[sc * HEADS + h] + ladst[dl * HEADS + h];
        a = (a > 0.f) ? a : NEG_SLOPE * a;
        const float e = __expf(a);
        atomicAdd(&acc[dl * HID + t], e * pr);
        if (slane) atomicAdd(&ssum[dl * HEADS + h], e);
    }
    __syncthreads();

    // epilogue: self-loop + normalize + bias, dense write
    for (int i = tid; i < lim * HID; i += 512) {
        const int dl = i >> 6;
        const int c  = i & 63;
        const int hh = c >> 4;
        const int n  = base + dl;
        float a = asrc[n * HEADS + hh] + ladst[dl * HEADS + hh];
        a = (a > 0.f) ? a : NEG_SLOPE * a;
        const float es = __expf(a);
        const float pn = bf2f(proj[(size_t)n * HID + c]);
        const float s  = ssum[dl * HEADS + hh] + es;
        out[(size_t)n * HID + c] = (acc[i] + es * pn) / s + bias[c];
    }
}

static inline size_t align16(size_t o) { return (o + 15) & ~(size_t)15; }

extern "C" void kernel_launch(void* const* d_in, const int* in_sizes, int n_in,
                              void* d_out, int out_size, void* d_ws, size_t ws_size,
                              hipStream_t stream)
{
    const float* x       = (const float*)d_in[0];
    const int*   ei      = (const int*)d_in[1];
    const float* W       = (const float*)d_in[2];
    const float* att_src = (const float*)d_in[3];
    const float* att_dst = (const float*)d_in[4];
    const float* bias    = (const float*)d_in[5];
    float* out           = (float*)d_out;

    const int n_nodes = in_sizes[0] / IN_CH;   // 50000
    const int n_edges = in_sizes[1] / 2;       // 1,000,000
    const int nblk    = (n_edges + SEG - 1) / SEG;       // 245
    const int nrange  = (n_nodes + RSZ - 1) / RSZ;       // 196

    const int* src = ei;
    const int* dst = ei + n_edges;

    // ---- workspace layout ----
    char* base = (char*)d_ws;
    size_t o = 0;
    unsigned short* proj = (unsigned short*)(base + o); o = align16(o + (size_t)n_nodes * HID * 2);
    float* asrc      = (float*)(base + o); o = align16(o + (size_t)n_nodes * HEADS * 4);
    float* adst      = (float*)(base + o); o = align16(o + (size_t)n_nodes * HEADS * 4);
    int*   cnt       = (int*)(base + o);   o = align16(o + (size_t)nblk * NRANGE * 4);
    int*   off       = (int*)(base + o);   o = align16(o + (size_t)nblk * NRANGE * 4);
    int*   coltot    = (int*)(base + o);   o = align16(o + NRANGE * 4);
    int*   colbase   = (int*)(base + o);   o = align16(o + (NRANGE + 16) * 4);
    unsigned int* ebuf = (unsigned int*)(base + o); o = align16(o + (size_t)n_edges * 4);

    proj_mfma_kernel<<<(n_nodes + 63) / 64, 256, 0, stream>>>(
        x, W, att_src, att_dst, proj, asrc, adst, coltot, n_nodes);

    count_kernel<<<nblk, 256, 0, stream>>>(dst, cnt, coltot, n_edges);
    colbase_kernel<<<1, 256, 0, stream>>>(coltot, colbase);
    colscan_kernel<<<NRANGE, 64, 0, stream>>>(cnt, colbase, off, nblk);
    bin_kernel<<<nblk, 256, 0, stream>>>(src, dst, off, ebuf, n_edges);

    range_agg_kernel<<<nrange, 512, 0, stream>>>(
        ebuf, colbase, proj, asrc, adst, bias, out, n_nodes);
}

// Round 10
// 206.482 us; speedup vs baseline: 2.9054x; 2.9054x over previous
//
#include <hip/hip_runtime.h>

#define IN_CH   128
#define HEADS   4
#define OUT_CH  16
#define HID     64
#define NEG_SLOPE 0.2f

#define LDA 136            // padded LDS row stride in bf16 elems

// counting-sort config: destination ranges of 512 nodes
#define RB      9                  // log2(range size)
#define RSZ     512                // nodes per destination range
#define NRANGE  128                // padded range count (98 real for N=50000)
#define SEG     4096               // edges per sort block
// ebuf packing: (dlocal << 23) | src   — src < 2^23, dlocal < 2^9

typedef __attribute__((ext_vector_type(8))) short short8;     // 8 bf16
typedef __attribute__((ext_vector_type(4))) float float4v;    // 4 fp32 acc

__device__ __forceinline__ unsigned short f2bf(float f) {
    unsigned int u = __float_as_uint(f);
    u += 0x7FFFu + ((u >> 16) & 1u);
    return (unsigned short)(u >> 16);
}
__device__ __forceinline__ float bf2f(unsigned short u) {
    return __uint_as_float(((unsigned int)u) << 16);
}

// ---------------------------------------------------------------------------
// Kernel A (fused): blocks [0, nblk_proj) do proj GEMM; the rest do the
// per-segment dest-range histogram (independent work, overlapped).
// proj: x @ W^T via bf16 MFMA, proj stored bf16; fused asrc/adst epilogue.
// ---------------------------------------------------------------------------
__global__ __launch_bounds__(256) void proj_count_kernel(
    const float* __restrict__ x,
    const float* __restrict__ W,
    const float* __restrict__ att_src,
    const float* __restrict__ att_dst,
    unsigned short* __restrict__ proj,   // [N, 64] bf16
    float* __restrict__ asrc,
    float* __restrict__ adst,
    const int* __restrict__ dst,
    int* __restrict__ cnt,
    int n_nodes, int n_edges, int nblk_proj)
{
    __shared__ unsigned short As[64 * LDA];
    __shared__ unsigned short Bs[64 * LDA];
    __shared__ int lc[NRANGE];

    const int tid = threadIdx.x;

    if (blockIdx.x >= nblk_proj) {
        // ---------------- count role ----------------
        const int b = blockIdx.x - nblk_proj;
        if (tid < NRANGE) lc[tid] = 0;
        __syncthreads();
        const int e0 = b * SEG;
        const int e1 = min(e0 + SEG, n_edges);
        for (int e = e0 + tid * 4; e < e1; e += 1024) {
            if (e + 4 <= e1) {
                const int4 d4 = *(const int4*)(dst + e);
                atomicAdd(&lc[d4.x >> RB], 1);
                atomicAdd(&lc[d4.y >> RB], 1);
                atomicAdd(&lc[d4.z >> RB], 1);
                atomicAdd(&lc[d4.w >> RB], 1);
            } else {
                for (int q = e; q < e1; ++q) atomicAdd(&lc[dst[q] >> RB], 1);
            }
        }
        __syncthreads();
        if (tid < NRANGE) cnt[b * NRANGE + tid] = lc[tid];
        return;
    }

    // ---------------- proj role ----------------
    const int n0 = blockIdx.x * 64;

    #pragma unroll
    for (int i = 0; i < 8; ++i) {
        int idx4 = i * 256 + tid;
        int row  = idx4 >> 5;
        int c4   = (idx4 & 31) * 4;
        float4 v = *(const float4*)(W + row * IN_CH + c4);
        ushort4 o;
        o.x = f2bf(v.x); o.y = f2bf(v.y); o.z = f2bf(v.z); o.w = f2bf(v.w);
        *(ushort4*)(&Bs[row * LDA + c4]) = o;
    }
    #pragma unroll
    for (int i = 0; i < 8; ++i) {
        int idx4 = i * 256 + tid;
        int row  = idx4 >> 5;
        int c4   = (idx4 & 31) * 4;
        int n    = n0 + row;
        float4 v = make_float4(0.f, 0.f, 0.f, 0.f);
        if (n < n_nodes) v = *(const float4*)(x + (size_t)n * IN_CH + c4);
        ushort4 o;
        o.x = f2bf(v.x); o.y = f2bf(v.y); o.z = f2bf(v.z); o.w = f2bf(v.w);
        *(ushort4*)(&As[row * LDA + c4]) = o;
    }
    __syncthreads();

    const int w    = tid >> 6;
    const int lane = tid & 63;
    const int l16  = lane & 15;
    const int quad = lane >> 4;

    float4v acc0 = {0.f,0.f,0.f,0.f};
    float4v acc1 = {0.f,0.f,0.f,0.f};
    float4v acc2 = {0.f,0.f,0.f,0.f};
    float4v acc3 = {0.f,0.f,0.f,0.f};

    const unsigned short* arow = &As[(w * 16 + l16) * LDA + quad * 8];
    const unsigned short* b0   = &Bs[( 0 + l16) * LDA + quad * 8];
    const unsigned short* b1   = &Bs[(16 + l16) * LDA + quad * 8];
    const unsigned short* b2   = &Bs[(32 + l16) * LDA + quad * 8];
    const unsigned short* b3   = &Bs[(48 + l16) * LDA + quad * 8];

    #pragma unroll
    for (int k0 = 0; k0 < IN_CH; k0 += 32) {
        short8 a  = *(const short8*)(arow + k0);
        acc0 = __builtin_amdgcn_mfma_f32_16x16x32_bf16(a, *(const short8*)(b0 + k0), acc0, 0, 0, 0);
        acc1 = __builtin_amdgcn_mfma_f32_16x16x32_bf16(a, *(const short8*)(b1 + k0), acc1, 0, 0, 0);
        acc2 = __builtin_amdgcn_mfma_f32_16x16x32_bf16(a, *(const short8*)(b2 + k0), acc2, 0, 0, 0);
        acc3 = __builtin_amdgcn_mfma_f32_16x16x32_bf16(a, *(const short8*)(b3 + k0), acc3, 0, 0, 0);
    }

    const float as0 = att_src[ 0 + l16], ad0 = att_dst[ 0 + l16];
    const float as1 = att_src[16 + l16], ad1 = att_dst[16 + l16];
    const float as2 = att_src[32 + l16], ad2 = att_dst[32 + l16];
    const float as3 = att_src[48 + l16], ad3 = att_dst[48 + l16];

    #pragma unroll
    for (int r = 0; r < 4; ++r) {
        const int n = n0 + w * 16 + quad * 4 + r;
        const bool ok = (n < n_nodes);
        float v0 = acc0[r], v1 = acc1[r], v2 = acc2[r], v3 = acc3[r];
        if (ok) {
            proj[(size_t)n * HID +  0 + l16] = f2bf(v0);
            proj[(size_t)n * HID + 16 + l16] = f2bf(v1);
            proj[(size_t)n * HID + 32 + l16] = f2bf(v2);
            proj[(size_t)n * HID + 48 + l16] = f2bf(v3);
        }
        float s0 = v0 * as0, s1 = v1 * as1, s2 = v2 * as2, s3 = v3 * as3;
        float d0 = v0 * ad0, d1 = v1 * ad1, d2 = v2 * ad2, d3 = v3 * ad3;
        #pragma unroll
        for (int off = 8; off >= 1; off >>= 1) {
            s0 += __shfl_down(s0, off, 16);
            s1 += __shfl_down(s1, off, 16);
            s2 += __shfl_down(s2, off, 16);
            s3 += __shfl_down(s3, off, 16);
            d0 += __shfl_down(d0, off, 16);
            d1 += __shfl_down(d1, off, 16);
            d2 += __shfl_down(d2, off, 16);
            d3 += __shfl_down(d3, off, 16);
        }
        if (ok && l16 == 0) {
            asrc[n * HEADS + 0] = s0;
            asrc[n * HEADS + 1] = s1;
            asrc[n * HEADS + 2] = s2;
            asrc[n * HEADS + 3] = s3;
            adst[n * HEADS + 0] = d0;
            adst[n * HEADS + 1] = d1;
            adst[n * HEADS + 2] = d2;
            adst[n * HEADS + 3] = d3;
        }
    }
}

// ---------------------------------------------------------------------------
// Kernel B: self-sufficient column scan. Block r (128 thr):
//  phase 1: every block computes ALL column totals from cnt (L2-hot, cheap)
//  phase 2: LDS exclusive scan over ranges -> colbase[r] (block r writes it)
//  phase 3: per-column prefix over segment blocks -> off[b][r]
// Replaces separate colbase kernel + coltot accumulation.
// ---------------------------------------------------------------------------
__global__ __launch_bounds__(128) void colscan_kernel(
    const int* __restrict__ cnt, int* __restrict__ colbase,
    int* __restrict__ off, int nblk)
{
    __shared__ int tot[NRANGE];
    __shared__ int excl[NRANGE + 1];
    __shared__ int wtot[2];

    const int r = blockIdx.x;
    const int t = threadIdx.x;

    // phase 1: column totals
    int s = 0;
    for (int b = 0; b < nblk; ++b) s += cnt[b * NRANGE + t];
    tot[t] = s;

    // phase 2: exclusive scan of tot[0..127] (two waves + LDS carry)
    const int lane = t & 63;
    const int wv   = t >> 6;
    int sc = s;
    #pragma unroll
    for (int o = 1; o < 64; o <<= 1) {
        int u = __shfl_up(sc, o);
        if (lane >= o) sc += u;
    }
    if (lane == 63) wtot[wv] = sc;
    __syncthreads();
    const int add = (wv == 1) ? wtot[0] : 0;
    excl[t] = add + sc - s;
    if (t == NRANGE - 1) excl[NRANGE] = add + sc;
    __syncthreads();

    if (t == 0) colbase[r] = excl[r];
    if (r == NRANGE - 1 && t == 0) colbase[NRANGE] = excl[NRANGE];

    // phase 3: prefix over segment blocks for column r (first wave only)
    if (wv == 0) {
        int carry = excl[r];
        for (int c0 = 0; c0 < nblk; c0 += 64) {
            const int b = c0 + lane;
            int v = (b < nblk) ? cnt[b * NRANGE + r] : 0;
            int p = v;
            #pragma unroll
            for (int o = 1; o < 64; o <<= 1) {
                int u = __shfl_up(p, o);
                if (lane >= o) p += u;
            }
            if (b < nblk) off[b * NRANGE + r] = carry + p - v;
            carry += __shfl(p, 63);
        }
    }
}

// ---------------------------------------------------------------------------
// Kernel C: bin edges into range-major ebuf, packed (dlocal<<23)|src (uint).
// Block-exclusive windows -> dense stores.
// ---------------------------------------------------------------------------
__global__ __launch_bounds__(256) void bin_kernel(
    const int* __restrict__ src, const int* __restrict__ dst,
    const int* __restrict__ off, unsigned int* __restrict__ ebuf, int n_edges)
{
    __shared__ int lpos[NRANGE];
    const int b = blockIdx.x;
    if (threadIdx.x < NRANGE) lpos[threadIdx.x] = off[b * NRANGE + threadIdx.x];
    __syncthreads();
    const int e0 = b * SEG;
    const int e1 = min(e0 + SEG, n_edges);
    for (int e = e0 + threadIdx.x * 4; e < e1; e += 1024) {
        if (e + 4 <= e1) {
            const int4 s4 = *(const int4*)(src + e);
            const int4 d4 = *(const int4*)(dst + e);
            {
                const int slot = atomicAdd(&lpos[d4.x >> RB], 1);
                ebuf[slot] = ((unsigned int)(d4.x & (RSZ - 1)) << 23) | (unsigned int)s4.x;
            }
            {
                const int slot = atomicAdd(&lpos[d4.y >> RB], 1);
                ebuf[slot] = ((unsigned int)(d4.y & (RSZ - 1)) << 23) | (unsigned int)s4.y;
            }
            {
                const int slot = atomicAdd(&lpos[d4.z >> RB], 1);
                ebuf[slot] = ((unsigned int)(d4.z & (RSZ - 1)) << 23) | (unsigned int)s4.z;
            }
            {
                const int slot = atomicAdd(&lpos[d4.w >> RB], 1);
                ebuf[slot] = ((unsigned int)(d4.w & (RSZ - 1)) << 23) | (unsigned int)s4.w;
            }
        } else {
            for (int q = e; q < e1; ++q) {
                const int d = dst[q];
                const int slot = atomicAdd(&lpos[d >> RB], 1);
                ebuf[slot] = ((unsigned int)(d & (RSZ - 1)) << 23) | (unsigned int)src[q];
            }
        }
    }
}

// ---------------------------------------------------------------------------
// Kernel D: per-range histogram + LDS exclusive scan + rsdeg write +
// LDS-atomic scatter into the range's csr window. One block/range.
// rsdeg[n] = {row_start, deg} packed for one uniform 8B load in gather.
// ---------------------------------------------------------------------------
__global__ __launch_bounds__(256) void range_csr_kernel(
    const unsigned int* __restrict__ ebuf, const int* __restrict__ colbase,
    int2* __restrict__ rsdeg, unsigned short* __restrict__ csr, int n_nodes)
{
    __shared__ int hist[RSZ];
    __shared__ int cur[RSZ];
    __shared__ int wsum[4];

    const int r    = blockIdx.x;
    const int base = r << RB;
    const int lim  = min(RSZ, n_nodes - base);
    const int tid  = threadIdx.x;

    for (int i = tid; i < RSZ; i += 256) hist[i] = 0;
    __syncthreads();

    const int s0 = colbase[r], s1 = colbase[r + 1];
    for (int j = s0 + tid; j < s1; j += 256)
        atomicAdd(&hist[ebuf[j] >> 23], 1);
    __syncthreads();

    // exclusive scan of hist[0..511]; thread t owns elements 2t, 2t+1
    const int h0 = hist[2 * tid], h1 = hist[2 * tid + 1];
    const int tsum = h0 + h1;
    const int lane = tid & 63;
    const int wv   = tid >> 6;
    int sc = tsum;
    #pragma unroll
    for (int o = 1; o < 64; o <<= 1) {
        int u = __shfl_up(sc, o);
        if (lane >= o) sc += u;
    }
    if (lane == 63) wsum[wv] = sc;
    __syncthreads();
    int woff = 0;
    for (int w = 0; w < wv; ++w) woff += wsum[w];
    const int start = s0 + woff + (sc - tsum);
    cur[2 * tid]     = start;
    cur[2 * tid + 1] = start + h0;
    __syncthreads();

    for (int i = tid; i < lim; i += 256)
        rsdeg[base + i] = make_int2(cur[i], hist[i]);
    __syncthreads();   // all reads of cur done before scatter mutates it

    for (int j = s0 + tid; j < s1; j += 256) {
        const unsigned int p = ebuf[j];
        const int slot = atomicAdd(&cur[p >> 23], 1);
        csr[slot] = (unsigned short)(p & 0x7FFFFFu);
    }
}

// ---------------------------------------------------------------------------
// Kernel E: gather = fused attention + aggregation + normalize + bias.
// One wave per node. csr read as broadcast uint4 (8 edge-ids per load).
// ---------------------------------------------------------------------------
__global__ __launch_bounds__(256) void gather_kernel(
    const unsigned short* __restrict__ proj,   // bf16
    const float* __restrict__ asrc,
    const float* __restrict__ adst,
    const int2* __restrict__ rsdeg,
    const unsigned short* __restrict__ csr,
    const float* __restrict__ bias,
    float* __restrict__ out,
    int n_nodes)
{
    const int n = blockIdx.x * 4 + (threadIdx.x >> 6);
    if (n >= n_nodes) return;
    const int t = threadIdx.x & 63;
    const int h = t >> 4;

    const float ad = adst[n * HEADS + h];
    const float bv = bias[t];

    float a0 = asrc[n * HEADS + h] + ad;
    a0 = (a0 > 0.f) ? a0 : NEG_SLOPE * a0;
    float s = __expf(a0);
    float acc = s * bf2f(proj[(size_t)n * HID + t]);

    const int2 rd   = rsdeg[n];
    const int start = __builtin_amdgcn_readfirstlane(rd.x);
    const int d     = __builtin_amdgcn_readfirstlane(rd.y);
    const int end   = start + d;

    int j = start;
    // scalar prologue to 8-edge (16B) alignment
    while (j < end && (j & 7)) {
        const int sj = csr[j];
        const float pj = bf2f(proj[(size_t)sj * HID + t]);
        float bj = asrc[sj * HEADS + h] + ad;
        bj = (bj > 0.f) ? bj : NEG_SLOPE * bj;
        const float ej = __expf(bj);
        acc = fmaf(ej, pj, acc);
        s += ej;
        ++j;
    }
    for (; j + 8 <= end; j += 8) {
        const uint4 u = *(const uint4*)(csr + j);   // 8 ushort ids
        int sid[8];
        sid[0] = u.x & 0xFFFF; sid[1] = u.x >> 16;
        sid[2] = u.y & 0xFFFF; sid[3] = u.y >> 16;
        sid[4] = u.z & 0xFFFF; sid[5] = u.z >> 16;
        sid[6] = u.w & 0xFFFF; sid[7] = u.w >> 16;
        float pv[8], av[8];
        #pragma unroll
        for (int k = 0; k < 8; ++k) pv[k] = bf2f(proj[(size_t)sid[k] * HID + t]);
        #pragma unroll
        for (int k = 0; k < 8; ++k) av[k] = asrc[sid[k] * HEADS + h] + ad;
        #pragma unroll
        for (int k = 0; k < 8; ++k) {
            float b = av[k];
            b = (b > 0.f) ? b : NEG_SLOPE * b;
            const float e = __expf(b);
            acc = fmaf(e, pv[k], acc);
            s += e;
        }
    }
    for (; j < end; ++j) {
        const int sj = csr[j];
        const float pj = bf2f(proj[(size_t)sj * HID + t]);
        float bj = asrc[sj * HEADS + h] + ad;
        bj = (bj > 0.f) ? bj : NEG_SLOPE * bj;
        const float ej = __expf(bj);
        acc = fmaf(ej, pj, acc);
        s += ej;
    }

    out[(size_t)n * HID + t] = acc / s + bv;
}

static inline size_t align16(size_t o) { return (o + 15) & ~(size_t)15; }

extern "C" void kernel_launch(void* const* d_in, const int* in_sizes, int n_in,
                              void* d_out, int out_size, void* d_ws, size_t ws_size,
                              hipStream_t stream)
{
    const float* x       = (const float*)d_in[0];
    const int*   ei      = (const int*)d_in[1];
    const float* W       = (const float*)d_in[2];
    const float* att_src = (const float*)d_in[3];
    const float* att_dst = (const float*)d_in[4];
    const float* bias    = (const float*)d_in[5];
    float* out           = (float*)d_out;

    const int n_nodes = in_sizes[0] / IN_CH;   // 50000
    const int n_edges = in_sizes[1] / 2;       // 1,000,000
    const int nblk    = (n_edges + SEG - 1) / SEG;       // 245
    const int nrange  = (n_nodes + RSZ - 1) / RSZ;       // 98
    const int nproj   = (n_nodes + 63) / 64;             // 782

    const int* src = ei;
    const int* dst = ei + n_edges;

    // ---- workspace layout ----
    char* base = (char*)d_ws;
    size_t o = 0;
    unsigned short* proj = (unsigned short*)(base + o); o = align16(o + (size_t)n_nodes * HID * 2);
    float* asrc      = (float*)(base + o); o = align16(o + (size_t)n_nodes * HEADS * 4);
    float* adst      = (float*)(base + o); o = align16(o + (size_t)n_nodes * HEADS * 4);
    int2*  rsdeg     = (int2*)(base + o);  o = align16(o + (size_t)n_nodes * 8);
    unsigned short* csr = (unsigned short*)(base + o); o = align16(o + (size_t)n_edges * 2);
    int*   cnt       = (int*)(base + o);   o = align16(o + (size_t)nblk * NRANGE * 4);
    int*   off       = (int*)(base + o);   o = align16(o + (size_t)nblk * NRANGE * 4);
    int*   colbase   = (int*)(base + o);   o = align16(o + (NRANGE + 16) * 4);
    unsigned int* ebuf = (unsigned int*)(base + o); o = align16(o + (size_t)n_edges * 4);

    proj_count_kernel<<<nproj + nblk, 256, 0, stream>>>(
        x, W, att_src, att_dst, proj, asrc, adst, dst, cnt,
        n_nodes, n_edges, nproj);

    colscan_kernel<<<NRANGE, 128, 0, stream>>>(cnt, colbase, off, nblk);

    bin_kernel<<<nblk, 256, 0, stream>>>(src, dst, off, ebuf, n_edges);

    range_csr_kernel<<<nrange, 256, 0, stream>>>(ebuf, colbase, rsdeg, csr, n_nodes);

    gather_kernel<<<(n_nodes + 3) / 4, 256, 0, stream>>>(
        proj, asrc, adst, rsdeg, csr, bias, out, n_nodes);
}

// Round 11
// 203.079 us; speedup vs baseline: 2.9541x; 1.0168x over previous
//
#include <hip/hip_runtime.h>

#define IN_CH   128
#define HEADS   4
#define OUT_CH  16
#define HID     64
#define NEG_SLOPE 0.2f
#define LOG2E   1.44269504088896340736f

#define LDA 136            // padded LDS row stride in bf16 elems

// counting-sort config: destination ranges of 256 nodes
#define RB      8                  // log2(range size)
#define RSZ     256                // nodes per destination range
#define NRANGE  256                // padded range count (196 real for N=50000)
#define SEG     4096               // edges per sort block
// ebuf packing: (dlocal << 24) | src   — src < 2^16, dlocal < 2^8

typedef __attribute__((ext_vector_type(8))) short short8;     // 8 bf16
typedef __attribute__((ext_vector_type(4))) float float4v;    // 4 fp32 acc

__device__ __forceinline__ unsigned short f2bf(float f) {
    unsigned int u = __float_as_uint(f);
    u += 0x7FFFu + ((u >> 16) & 1u);
    return (unsigned short)(u >> 16);
}
__device__ __forceinline__ float bf2f(unsigned short u) {
    return __uint_as_float(((unsigned int)u) << 16);
}

// ---------------------------------------------------------------------------
// Kernel A (fused): blocks [0, nblk_proj) do proj GEMM; the rest histogram
// edge dests per segment. asrc/adst are PRE-SCALED by log2(e) so gather can
// use native exp2 (lrelu commutes with positive scale -> identical math).
// ---------------------------------------------------------------------------
__global__ __launch_bounds__(256) void proj_count_kernel(
    const float* __restrict__ x,
    const float* __restrict__ W,
    const float* __restrict__ att_src,
    const float* __restrict__ att_dst,
    unsigned short* __restrict__ proj,   // [N, 64] bf16
    float* __restrict__ asrc,            // scaled by LOG2E
    float* __restrict__ adst,            // scaled by LOG2E
    const int* __restrict__ dst,
    int* __restrict__ cnt,
    int n_nodes, int n_edges, int nblk_proj)
{
    __shared__ unsigned short As[64 * LDA];
    __shared__ unsigned short Bs[64 * LDA];
    __shared__ int lc[NRANGE];

    const int tid = threadIdx.x;

    if (blockIdx.x >= nblk_proj) {
        // ---------------- count role ----------------
        const int b = blockIdx.x - nblk_proj;
        lc[tid] = 0;
        __syncthreads();
        const int e0 = b * SEG;
        const int e1 = min(e0 + SEG, n_edges);
        for (int e = e0 + tid * 4; e < e1; e += 1024) {
            if (e + 4 <= e1) {
                const int4 d4 = *(const int4*)(dst + e);
                atomicAdd(&lc[d4.x >> RB], 1);
                atomicAdd(&lc[d4.y >> RB], 1);
                atomicAdd(&lc[d4.z >> RB], 1);
                atomicAdd(&lc[d4.w >> RB], 1);
            } else {
                for (int q = e; q < e1; ++q) atomicAdd(&lc[dst[q] >> RB], 1);
            }
        }
        __syncthreads();
        cnt[b * NRANGE + tid] = lc[tid];
        return;
    }

    // ---------------- proj role ----------------
    const int n0 = blockIdx.x * 64;

    #pragma unroll
    for (int i = 0; i < 8; ++i) {
        int idx4 = i * 256 + tid;
        int row  = idx4 >> 5;
        int c4   = (idx4 & 31) * 4;
        float4 v = *(const float4*)(W + row * IN_CH + c4);
        ushort4 o;
        o.x = f2bf(v.x); o.y = f2bf(v.y); o.z = f2bf(v.z); o.w = f2bf(v.w);
        *(ushort4*)(&Bs[row * LDA + c4]) = o;
    }
    #pragma unroll
    for (int i = 0; i < 8; ++i) {
        int idx4 = i * 256 + tid;
        int row  = idx4 >> 5;
        int c4   = (idx4 & 31) * 4;
        int n    = n0 + row;
        float4 v = make_float4(0.f, 0.f, 0.f, 0.f);
        if (n < n_nodes) v = *(const float4*)(x + (size_t)n * IN_CH + c4);
        ushort4 o;
        o.x = f2bf(v.x); o.y = f2bf(v.y); o.z = f2bf(v.z); o.w = f2bf(v.w);
        *(ushort4*)(&As[row * LDA + c4]) = o;
    }
    __syncthreads();

    const int w    = tid >> 6;
    const int lane = tid & 63;
    const int l16  = lane & 15;
    const int quad = lane >> 4;

    float4v acc0 = {0.f,0.f,0.f,0.f};
    float4v acc1 = {0.f,0.f,0.f,0.f};
    float4v acc2 = {0.f,0.f,0.f,0.f};
    float4v acc3 = {0.f,0.f,0.f,0.f};

    const unsigned short* arow = &As[(w * 16 + l16) * LDA + quad * 8];
    const unsigned short* b0   = &Bs[( 0 + l16) * LDA + quad * 8];
    const unsigned short* b1   = &Bs[(16 + l16) * LDA + quad * 8];
    const unsigned short* b2   = &Bs[(32 + l16) * LDA + quad * 8];
    const unsigned short* b3   = &Bs[(48 + l16) * LDA + quad * 8];

    #pragma unroll
    for (int k0 = 0; k0 < IN_CH; k0 += 32) {
        short8 a  = *(const short8*)(arow + k0);
        acc0 = __builtin_amdgcn_mfma_f32_16x16x32_bf16(a, *(const short8*)(b0 + k0), acc0, 0, 0, 0);
        acc1 = __builtin_amdgcn_mfma_f32_16x16x32_bf16(a, *(const short8*)(b1 + k0), acc1, 0, 0, 0);
        acc2 = __builtin_amdgcn_mfma_f32_16x16x32_bf16(a, *(const short8*)(b2 + k0), acc2, 0, 0, 0);
        acc3 = __builtin_amdgcn_mfma_f32_16x16x32_bf16(a, *(const short8*)(b3 + k0), acc3, 0, 0, 0);
    }

    const float as0 = att_src[ 0 + l16], ad0 = att_dst[ 0 + l16];
    const float as1 = att_src[16 + l16], ad1 = att_dst[16 + l16];
    const float as2 = att_src[32 + l16], ad2 = att_dst[32 + l16];
    const float as3 = att_src[48 + l16], ad3 = att_dst[48 + l16];

    #pragma unroll
    for (int r = 0; r < 4; ++r) {
        const int n = n0 + w * 16 + quad * 4 + r;
        const bool ok = (n < n_nodes);
        float v0 = acc0[r], v1 = acc1[r], v2 = acc2[r], v3 = acc3[r];
        if (ok) {
            proj[(size_t)n * HID +  0 + l16] = f2bf(v0);
            proj[(size_t)n * HID + 16 + l16] = f2bf(v1);
            proj[(size_t)n * HID + 32 + l16] = f2bf(v2);
            proj[(size_t)n * HID + 48 + l16] = f2bf(v3);
        }
        float s0 = v0 * as0, s1 = v1 * as1, s2 = v2 * as2, s3 = v3 * as3;
        float d0 = v0 * ad0, d1 = v1 * ad1, d2 = v2 * ad2, d3 = v3 * ad3;
        #pragma unroll
        for (int off = 8; off >= 1; off >>= 1) {
            s0 += __shfl_down(s0, off, 16);
            s1 += __shfl_down(s1, off, 16);
            s2 += __shfl_down(s2, off, 16);
            s3 += __shfl_down(s3, off, 16);
            d0 += __shfl_down(d0, off, 16);
            d1 += __shfl_down(d1, off, 16);
            d2 += __shfl_down(d2, off, 16);
            d3 += __shfl_down(d3, off, 16);
        }
        if (ok && l16 == 0) {
            asrc[n * HEADS + 0] = s0 * LOG2E;
            asrc[n * HEADS + 1] = s1 * LOG2E;
            asrc[n * HEADS + 2] = s2 * LOG2E;
            asrc[n * HEADS + 3] = s3 * LOG2E;
            adst[n * HEADS + 0] = d0 * LOG2E;
            adst[n * HEADS + 1] = d1 * LOG2E;
            adst[n * HEADS + 2] = d2 * LOG2E;
            adst[n * HEADS + 3] = d3 * LOG2E;
        }
    }
}

// ---------------------------------------------------------------------------
// Kernel B: bin edges into range-major ebuf, packed (dlocal<<24)|src.
// Each block derives its own window offsets from the L2-hot cnt matrix:
//   lpos[t] = exclusive-prefix-over-ranges(coltot)[t] + sum_{b'<b} cnt[b'][t]
// (replaces the separate colscan kernel + off/colbase buffers)
// ---------------------------------------------------------------------------
__global__ __launch_bounds__(256) void bin_kernel(
    const int* __restrict__ src, const int* __restrict__ dst,
    const int* __restrict__ cnt, unsigned int* __restrict__ ebuf,
    int n_edges, int nblk)
{
    __shared__ int lpos[NRANGE];
    __shared__ int wsum[4];

    const int b = blockIdx.x;
    const int t = threadIdx.x;

    int tot = 0, pre = 0;
    for (int b2 = 0; b2 < nblk; ++b2) {
        const int v = cnt[b2 * NRANGE + t];
        tot += v;
        if (b2 < b) pre += v;
    }
    const int lane = t & 63;
    const int wv   = t >> 6;
    int sc = tot;
    #pragma unroll
    for (int o = 1; o < 64; o <<= 1) {
        int u = __shfl_up(sc, o);
        if (lane >= o) sc += u;
    }
    if (lane == 63) wsum[wv] = sc;
    __syncthreads();
    int add = 0;
    for (int w = 0; w < wv; ++w) add += wsum[w];
    lpos[t] = add + sc - tot + pre;      // excl[t] + prefix over earlier blocks
    __syncthreads();

    const int e0 = b * SEG;
    const int e1 = min(e0 + SEG, n_edges);
    for (int e = e0 + t * 4; e < e1; e += 1024) {
        if (e + 4 <= e1) {
            const int4 s4 = *(const int4*)(src + e);
            const int4 d4 = *(const int4*)(dst + e);
            {
                const int slot = atomicAdd(&lpos[d4.x >> RB], 1);
                ebuf[slot] = ((unsigned int)(d4.x & (RSZ - 1)) << 24) | (unsigned int)s4.x;
            }
            {
                const int slot = atomicAdd(&lpos[d4.y >> RB], 1);
                ebuf[slot] = ((unsigned int)(d4.y & (RSZ - 1)) << 24) | (unsigned int)s4.y;
            }
            {
                const int slot = atomicAdd(&lpos[d4.z >> RB], 1);
                ebuf[slot] = ((unsigned int)(d4.z & (RSZ - 1)) << 24) | (unsigned int)s4.z;
            }
            {
                const int slot = atomicAdd(&lpos[d4.w >> RB], 1);
                ebuf[slot] = ((unsigned int)(d4.w & (RSZ - 1)) << 24) | (unsigned int)s4.w;
            }
        } else {
            for (int q = e; q < e1; ++q) {
                const int d = dst[q];
                const int slot = atomicAdd(&lpos[d >> RB], 1);
                ebuf[slot] = ((unsigned int)(d & (RSZ - 1)) << 24) | (unsigned int)src[q];
            }
        }
    }
}

// ---------------------------------------------------------------------------
// Kernel C: per-range histogram + LDS scan + rsdeg write + LDS-atomic
// scatter into the range's csr window. Derives its own colbase from cnt.
// ---------------------------------------------------------------------------
__global__ __launch_bounds__(256) void range_csr_kernel(
    const unsigned int* __restrict__ ebuf, const int* __restrict__ cnt,
    int2* __restrict__ rsdeg, unsigned short* __restrict__ csr,
    int n_nodes, int nblk)
{
    __shared__ int excl_l[NRANGE];
    __shared__ int tot_l[NRANGE];
    __shared__ int hist[RSZ];
    __shared__ int cur[RSZ];
    __shared__ int wsum[4];

    const int r    = blockIdx.x;
    const int base = r << RB;
    const int lim  = min(RSZ, n_nodes - base);
    const int tid  = threadIdx.x;
    const int lane = tid & 63;
    const int wv   = tid >> 6;

    // column totals + exclusive scan over ranges (from L2-hot cnt)
    int tot = 0;
    for (int b2 = 0; b2 < nblk; ++b2) tot += cnt[b2 * NRANGE + tid];
    int sc = tot;
    #pragma unroll
    for (int o = 1; o < 64; o <<= 1) {
        int u = __shfl_up(sc, o);
        if (lane >= o) sc += u;
    }
    if (lane == 63) wsum[wv] = sc;
    hist[tid] = 0;                  // zero hist while scan carries settle
    __syncthreads();
    int add = 0;
    for (int w = 0; w < wv; ++w) add += wsum[w];
    excl_l[tid] = add + sc - tot;
    tot_l[tid]  = tot;
    __syncthreads();

    const int s0 = excl_l[r];
    const int s1 = s0 + tot_l[r];

    for (int j = s0 + tid; j < s1; j += 256)
        atomicAdd(&hist[ebuf[j] >> 24], 1);
    __syncthreads();

    // exclusive scan of hist[0..255]; thread t owns one element
    const int hv = hist[tid];
    int hc = hv;
    #pragma unroll
    for (int o = 1; o < 64; o <<= 1) {
        int u = __shfl_up(hc, o);
        if (lane >= o) hc += u;
    }
    __syncthreads();               // wsum reuse barrier
    if (lane == 63) wsum[wv] = hc;
    __syncthreads();
    int hadd = 0;
    for (int w = 0; w < wv; ++w) hadd += wsum[w];
    const int start = s0 + hadd + hc - hv;
    cur[tid] = start;
    if (tid < lim) rsdeg[base + tid] = make_int2(start, hv);
    __syncthreads();

    for (int j = s0 + tid; j < s1; j += 256) {
        const unsigned int p = ebuf[j];
        const int slot = atomicAdd(&cur[p >> 24], 1);
        csr[slot] = (unsigned short)p;     // src < 65536
    }
}

// ---------------------------------------------------------------------------
// Kernel D: gather = fused attention + aggregation + normalize + bias.
// One wave per node. Edge ids forced to SGPR (readfirstlane) so proj/asrc
// gathers use scalar-base addressing (addr math on SALU). Logits are
// pre-scaled by log2(e) -> native exp2f. XCD-swizzled block mapping keeps
// contiguous csr windows on one XCD's L2.
// ---------------------------------------------------------------------------
__global__ __launch_bounds__(256) void gather_kernel(
    const unsigned short* __restrict__ proj,   // bf16
    const float* __restrict__ asrc,            // scaled
    const float* __restrict__ adst,            // scaled
    const int2* __restrict__ rsdeg,
    const unsigned short* __restrict__ csr,
    const float* __restrict__ bias,
    float* __restrict__ out,
    int n_nodes, int chunk)
{
    // swizzle: 8 consecutive bids -> 8 XCDs; give each XCD a contiguous span
    const int nb2 = (blockIdx.x & 7) * chunk + (blockIdx.x >> 3);
    const int n = nb2 * 4 + (threadIdx.x >> 6);
    if (n >= n_nodes) return;
    const int t = threadIdx.x & 63;
    const int h = t >> 4;

    const float ad = adst[n * HEADS + h];
    const float bv = bias[t];

    float z0 = asrc[n * HEADS + h] + ad;
    z0 = fmaxf(z0, NEG_SLOPE * z0);            // leaky-relu (scaled domain)
    float s = exp2f(z0);
    float acc = s * bf2f(proj[(size_t)n * HID + t]);

    const int2 rd   = rsdeg[n];
    const int start = __builtin_amdgcn_readfirstlane(rd.x);
    const int d     = __builtin_amdgcn_readfirstlane(rd.y);
    const int end   = start + d;

    int j = start;
    for (; j + 8 <= end; j += 8) {
        int sid[8];
        #pragma unroll
        for (int k = 0; k < 8; ++k)
            sid[k] = __builtin_amdgcn_readfirstlane((int)csr[j + k]);
        float pv[8], av[8];
        #pragma unroll
        for (int k = 0; k < 8; ++k) pv[k] = bf2f(proj[sid[k] * HID + t]);
        #pragma unroll
        for (int k = 0; k < 8; ++k) av[k] = asrc[sid[k] * HEADS + h] + ad;
        #pragma unroll
        for (int k = 0; k < 8; ++k) {
            const float y = fmaxf(av[k], NEG_SLOPE * av[k]);
            const float e = exp2f(y);
            acc = fmaf(e, pv[k], acc);
            s += e;
        }
    }
    for (; j < end; ++j) {
        const int sj = __builtin_amdgcn_readfirstlane((int)csr[j]);
        const float pj = bf2f(proj[sj * HID + t]);
        float y = asrc[sj * HEADS + h] + ad;
        y = fmaxf(y, NEG_SLOPE * y);
        const float e = exp2f(y);
        acc = fmaf(e, pj, acc);
        s += e;
    }

    out[(size_t)n * HID + t] = acc / s + bv;
}

static inline size_t align16(size_t o) { return (o + 15) & ~(size_t)15; }

extern "C" void kernel_launch(void* const* d_in, const int* in_sizes, int n_in,
                              void* d_out, int out_size, void* d_ws, size_t ws_size,
                              hipStream_t stream)
{
    const float* x       = (const float*)d_in[0];
    const int*   ei      = (const int*)d_in[1];
    const float* W       = (const float*)d_in[2];
    const float* att_src = (const float*)d_in[3];
    const float* att_dst = (const float*)d_in[4];
    const float* bias    = (const float*)d_in[5];
    float* out           = (float*)d_out;

    const int n_nodes = in_sizes[0] / IN_CH;   // 50000
    const int n_edges = in_sizes[1] / 2;       // 1,000,000
    const int nblk    = (n_edges + SEG - 1) / SEG;       // 245
    const int nrange  = (n_nodes + RSZ - 1) / RSZ;       // 196
    const int nproj   = (n_nodes + 63) / 64;             // 782

    const int* src = ei;
    const int* dst = ei + n_edges;

    // ---- workspace layout ----
    char* base = (char*)d_ws;
    size_t o = 0;
    unsigned short* proj = (unsigned short*)(base + o); o = align16(o + (size_t)n_nodes * HID * 2);
    float* asrc      = (float*)(base + o); o = align16(o + (size_t)n_nodes * HEADS * 4);
    float* adst      = (float*)(base + o); o = align16(o + (size_t)n_nodes * HEADS * 4);
    int2*  rsdeg     = (int2*)(base + o);  o = align16(o + (size_t)n_nodes * 8);
    unsigned short* csr = (unsigned short*)(base + o); o = align16(o + (size_t)n_edges * 2);
    int*   cnt       = (int*)(base + o);   o = align16(o + (size_t)nblk * NRANGE * 4);
    unsigned int* ebuf = (unsigned int*)(base + o); o = align16(o + (size_t)n_edges * 4);

    proj_count_kernel<<<nproj + nblk, 256, 0, stream>>>(
        x, W, att_src, att_dst, proj, asrc, adst, dst, cnt,
        n_nodes, n_edges, nproj);

    bin_kernel<<<nblk, 256, 0, stream>>>(src, dst, cnt, ebuf, n_edges, nblk);

    range_csr_kernel<<<nrange, 256, 0, stream>>>(
        ebuf, cnt, rsdeg, csr, n_nodes, nblk);

    const int nb4   = (n_nodes + 3) / 4;                 // 12500
    const int chunk = (nb4 + 7) / 8;                     // 1563
    gather_kernel<<<chunk * 8, 256, 0, stream>>>(
        proj, asrc, adst, rsdeg, csr, bias, out, n_nodes, chunk);
}